// Round 7
// baseline (577.337 us; speedup 1.0000x reference)
//
#include <hip/hip_runtime.h>

typedef __bf16 bf16;
typedef __attribute__((ext_vector_type(8))) __bf16 bf16x8;
typedef __attribute__((ext_vector_type(4))) __bf16 bf16x4;
typedef __attribute__((ext_vector_type(4))) float f32x4;

#define GLL16(gptr, lptr)                                                      \
  __builtin_amdgcn_global_load_lds(                                            \
      (const __attribute__((address_space(1))) void*)(gptr),                   \
      (__attribute__((address_space(3))) void*)(lptr), 16, 0, 0)

__device__ __forceinline__ f32x4 mfma_bf16(bf16x8 a, bf16x8 b, f32x4 c) {
  return __builtin_amdgcn_mfma_f32_16x16x32_bf16(a, b, c, 0, 0, 0);
}

// ---------------- fp32 -> bf16 convert (vectorized) ----------------
__global__ __launch_bounds__(256) void k_cvt_f32_bf16(
    const float* __restrict__ in, bf16* __restrict__ out, int n4) {
  int i = blockIdx.x * blockDim.x + threadIdx.x;
  if (i < n4) {
    f32x4 v = ((const f32x4*)in)[i];
    bf16x4 o;
    o[0] = (bf16)v[0]; o[1] = (bf16)v[1]; o[2] = (bf16)v[2]; o[3] = (bf16)v[3];
    ((bf16x4*)out)[i] = o;
  }
}

// ------------- transpose + convert: out[n][k] = (bf16)in[k][n] -------------
__global__ __launch_bounds__(256) void k_transpose_cvt(
    const float* __restrict__ in, bf16* __restrict__ out, int R, int C) {
  __shared__ float tile[64][65];
  const int t = threadIdx.x;
  const int r0 = blockIdx.y * 64, c0 = blockIdx.x * 64;
  const int tc = t & 63, tr = t >> 6;
#pragma unroll
  for (int i = 0; i < 16; ++i) {
    int r = tr + i * 4;
    tile[r][tc] = in[(size_t)(r0 + r) * C + c0 + tc];
  }
  __syncthreads();
#pragma unroll
  for (int i = 0; i < 16; ++i) {
    int r = tr + i * 4;
    out[(size_t)(c0 + r) * R + r0 + tc] = (bf16)tile[tc][r];
  }
}

// ---------------- bf16 GEMM, B pre-transposed (Bt[N][K]) ----------------
// MODE 0: bf16 flat [M][N]; MODE 1: f32 flat [M][N];
// MODE 2: split head-major QKV — Q,K:[B*H][2048][128]; V TRANSPOSED:
//         VT[B*H][128][2048] so attention PV reads are contiguous rows.
template <int N, int K, int MODE>
__global__ __launch_bounds__(256) void k_gemm_bt(
    const bf16* __restrict__ A, const bf16* __restrict__ Bt,
    const float* __restrict__ bias, void* __restrict__ C0,
    void* __restrict__ C1, void* __restrict__ C2) {
  __shared__ __align__(16) unsigned char lds[16384];
  unsigned char* ldsA = lds;
  unsigned char* ldsB = lds + 8192;
  const int t = threadIdx.x, w = t >> 6, lane = t & 63;
  const int g = lane >> 4, c15 = lane & 15;
  const int wr = w >> 1, wc = w & 1;
  const int m0 = blockIdx.y * 128, n0 = blockIdx.x * 128;

  const int ch = w * 64 + lane;
  const bf16* gA0 = A + (size_t)(m0 + (ch >> 2)) * K + (ch & 3) * 8;
  const bf16* gA1 = A + (size_t)(m0 + ((ch + 256) >> 2)) * K + (ch & 3) * 8;
  const bf16* gB0 = Bt + (size_t)(n0 + (ch >> 2)) * K + (ch & 3) * 8;
  const bf16* gB1 = Bt + (size_t)(n0 + ((ch + 256) >> 2)) * K + (ch & 3) * 8;
  const unsigned l0 = (unsigned)(w * 64) * 16;

  f32x4 acc[4][4];
#pragma unroll
  for (int m = 0; m < 4; ++m)
#pragma unroll
    for (int n = 0; n < 4; ++n) acc[m][n] = (f32x4){0.f, 0.f, 0.f, 0.f};

  for (int kt = 0; kt < K / 32; ++kt) {
    GLL16(gA0, ldsA + l0);
    GLL16(gA1, ldsA + l0 + 4096);
    GLL16(gB0, ldsB + l0);
    GLL16(gB1, ldsB + l0 + 4096);
    gA0 += 32; gA1 += 32; gB0 += 32; gB1 += 32;
    __syncthreads();

    bf16x8 af[4], bfr[4];
#pragma unroll
    for (int m = 0; m < 4; ++m)
      af[m] = *(const bf16x8*)(ldsA + (wr * 64 + m * 16 + c15) * 64 + g * 16);
#pragma unroll
    for (int n = 0; n < 4; ++n)
      bfr[n] = *(const bf16x8*)(ldsB + (wc * 64 + n * 16 + c15) * 64 + g * 16);
#pragma unroll
    for (int m = 0; m < 4; ++m)
#pragma unroll
      for (int n = 0; n < 4; ++n)
        acc[m][n] = mfma_bf16(af[m], bfr[n], acc[m][n]);
    __syncthreads();
  }

  bf16* sbase = nullptr;
  int sec = 0;
  if constexpr (MODE == 2) {
    sec = n0 >> 11;
    const int hh = (n0 >> 7) & 15;
    sbase = (bf16*)(sec == 0 ? C0 : sec == 1 ? C1 : C2) +
            (size_t)hh * 2048 * 128;
  }

#pragma unroll
  for (int n = 0; n < 4; ++n) {
    const int col = n0 + wc * 64 + n * 16 + c15;
    const float bs = bias[col];
#pragma unroll
    for (int m = 0; m < 4; ++m)
#pragma unroll
      for (int r = 0; r < 4; ++r) {
        const int row = m0 + wr * 64 + m * 16 + g * 4 + r;
        const float v = acc[m][n][r] + bs;
        if constexpr (MODE == 0) {
          ((bf16*)C0)[(size_t)row * N + col] = (bf16)v;
        } else if constexpr (MODE == 1) {
          ((float*)C0)[(size_t)row * N + col] = v;
        } else {
          const int bb = row >> 11, srow = row & 2047;
          const int d = wc * 64 + n * 16 + c15;
          if (sec == 2)  // V: transposed [bh][128][2048]
            sbase[(size_t)bb * 16 * 2048 * 128 + (size_t)d * 2048 + srow] =
                (bf16)v;
          else
            sbase[((size_t)bb * 16 * 2048 + srow) * 128 + d] = (bf16)v;
        }
      }
  }
}

// ---------- causal flash attention, 2-way kv-split, barrier-free ----------
// Qb/Kb: [B*H][2048][128] bf16 ; VT: [B*H][128][2048] bf16 (transposed)
// ctx: [B*S][2048] bf16
// oP: [bh][qt16][slot][64][128] bf16 ; mlP: [bh][qt16][slot][2][64] f32
// Roles per bh (32 blocks): role<16 = A (long tile 31-role, kv 0..15, slot 0,
// never masked); role>=16 = B (long tile kv 16..qt -> slot 1, then short -> ctx).
__global__ __launch_bounds__(256) void k_attn(
    const bf16* __restrict__ Qb, const bf16* __restrict__ Kb,
    const bf16* __restrict__ VT, bf16* __restrict__ ctx,
    bf16* __restrict__ oP, float* __restrict__ mlP) {
  __shared__ __align__(16) unsigned char P[4][2048];  // per-wave, no barriers
  const int t = threadIdx.x, w = t >> 6, lane = t & 63;
  const int g = lane >> 4, c = lane & 15;
  const int L = (int)blockIdx.x;            // 0..1023
  const int bh = (L & 7) + 8 * (L >> 8);    // same bh -> same XCD (L%8 const)
  const int role = (L >> 3) & 31;
  const int b = bh >> 4, h = bh & 15;
  const size_t hb = (size_t)bh * 2048 * 128;
  const bf16* Qh = Qb + hb;
  const bf16* Kh = Kb + hb;
  const bf16* Vh = VT + hb;  // [128][2048]
  const float sc = 0.08838834764831845f * 1.4426950408889634f;  // scale*log2e

  const int nph = (role < 16) ? 1 : 2;
  for (int ph = 0; ph < nph; ++ph) {
    int qt, kv_begin, kv_end, mode;  // mode: 0=ctx, 1=slot0, 2=slot1
    if (role < 16) {
      qt = 31 - role; kv_begin = 0; kv_end = 16; mode = 1;
    } else if (ph == 0) {
      qt = 31 - (role - 16); kv_begin = 16; kv_end = qt + 1; mode = 2;
    } else {
      qt = role - 16; kv_begin = 0; kv_end = qt + 1; mode = 0;
    }
    const int q0 = qt * 64;
    const int qb = q0 + w * 16;

    bf16x8 qf[4];
    {
      const bf16* qp = Qh + (size_t)(qb + c) * 128;
#pragma unroll
      for (int s = 0; s < 4; ++s) qf[s] = *(const bf16x8*)(qp + s * 32 + g * 8);
    }

    f32x4 o[8];
#pragma unroll
    for (int n = 0; n < 8; ++n) o[n] = (f32x4){0.f, 0.f, 0.f, 0.f};
    float mrun[4] = {-3e38f, -3e38f, -3e38f, -3e38f};
    float lrun[4] = {0.f, 0.f, 0.f, 0.f};

    for (int kt = kv_begin; kt < kv_end; ++kt) {
      const int kv0 = kt * 64;

      // S = Q K^T (K compact rows, L2-resident)
      float p[4][4];
      float mt[4] = {-3e38f, -3e38f, -3e38f, -3e38f};
      const bool diag = (kv0 == q0);  // only the diagonal tile needs masking
#pragma unroll
      for (int tt = 0; tt < 4; ++tt) {
        f32x4 s4 = (f32x4){0.f, 0.f, 0.f, 0.f};
        const bf16* kp = Kh + (size_t)(kv0 + tt * 16 + c) * 128;
#pragma unroll
        for (int s = 0; s < 4; ++s) {
          bf16x8 kf = *(const bf16x8*)(kp + s * 32 + g * 8);
          s4 = mfma_bf16(qf[s], kf, s4);
        }
        const int kvi = kv0 + tt * 16 + c;
#pragma unroll
        for (int r = 0; r < 4; ++r) {
          float v = s4[r] * sc;
          if (diag) {
            const int qr = qb + g * 4 + r;
            v = (kvi <= qr) ? v : -1e30f;
          }
          p[tt][r] = v;
          mt[r] = fmaxf(mt[r], v);
        }
      }
#pragma unroll
      for (int r = 0; r < 4; ++r) {
        float m = mt[r];
        m = fmaxf(m, __shfl_xor(m, 1));
        m = fmaxf(m, __shfl_xor(m, 2));
        m = fmaxf(m, __shfl_xor(m, 4));
        m = fmaxf(m, __shfl_xor(m, 8));
        mt[r] = m;
      }
      float corr[4];
#pragma unroll
      for (int r = 0; r < 4; ++r) {
        const float mn = fmaxf(mrun[r], mt[r]);
        corr[r] = exp2f(mrun[r] - mn);
        mrun[r] = mn;
      }
#pragma unroll
      for (int r = 0; r < 4; ++r) {
        float s = 0.f;
#pragma unroll
        for (int tt = 0; tt < 4; ++tt) {
          const float e = exp2f(p[tt][r] - mrun[r]);
          p[tt][r] = e;
          s += e;
        }
        s += __shfl_xor(s, 1);
        s += __shfl_xor(s, 2);
        s += __shfl_xor(s, 4);
        s += __shfl_xor(s, 8);
        lrun[r] = lrun[r] * corr[r] + s;
      }
#pragma unroll
      for (int n = 0; n < 8; ++n)
#pragma unroll
        for (int r = 0; r < 4; ++r) o[n][r] *= corr[r];

      // store P (bf16) to per-wave LDS tile (XOR-swizzled rows); wave-private,
      // no barrier needed — same wave reads it back below.
#pragma unroll
      for (int tt = 0; tt < 4; ++tt)
#pragma unroll
        for (int r = 0; r < 4; ++r) {
          const int row = g * 4 + r;
          const int colb = (tt * 16 + c) * 2;
          *(bf16*)(&P[w][row * 128 + (colb ^ ((row & 7) << 4))]) =
              (bf16)p[tt][r];
        }

      // PV: o += P(16x64) * V(64x128); V read directly from VT rows (L2)
#pragma unroll
      for (int ks = 0; ks < 2; ++ks) {
        bf16x8 pa = *(const bf16x8*)(&P[w][c * 128 +
                                           ((ks * 64 + g * 16) ^ ((c & 7) << 4))]);
#pragma unroll
        for (int n = 0; n < 8; ++n) {
          bf16x8 vb = *(const bf16x8*)(Vh + (size_t)(n * 16 + c) * 2048 + kv0 +
                                       ks * 32 + g * 8);
          o[n] = mfma_bf16(pa, vb, o[n]);
        }
      }
    }

    if (mode == 0) {
      float inv[4];
#pragma unroll
      for (int r = 0; r < 4; ++r) inv[r] = 1.0f / lrun[r];
#pragma unroll
      for (int n = 0; n < 8; ++n)
#pragma unroll
        for (int r = 0; r < 4; ++r) {
          const int row = qb + g * 4 + r;
          ctx[(size_t)(b * 2048 + row) * 2048 + h * 128 + n * 16 + c] =
              (bf16)(o[n][r] * inv[r]);
        }
    } else {
      const int slot = mode - 1;
      const size_t pb = ((size_t)(bh * 16 + (qt - 16)) * 2 + slot);
      bf16* op = oP + pb * 64 * 128;
#pragma unroll
      for (int n = 0; n < 8; ++n)
#pragma unroll
        for (int r = 0; r < 4; ++r) {
          const int row = w * 16 + g * 4 + r;
          op[(size_t)row * 128 + n * 16 + c] = (bf16)o[n][r];  // unnormalized
        }
      if (c == 0) {
        float* mp = mlP + pb * 2 * 64;
#pragma unroll
        for (int r = 0; r < 4; ++r) {
          const int row = w * 16 + g * 4 + r;
          mp[row] = mrun[r];
          mp[64 + row] = lrun[r];
        }
      }
    }
  }
}

// ---------------- merge two kv-split partials -> ctx ----------------
__global__ __launch_bounds__(256) void k_merge(const bf16* __restrict__ oP,
                                               const float* __restrict__ mlP,
                                               bf16* __restrict__ ctx) {
  const int bh = blockIdx.y, qt16 = blockIdx.x;
  const int t = threadIdx.x;
  const int row = t >> 2, qq = t & 3;  // 64 rows x 4 col-quarters
  const size_t base = (size_t)(bh * 16 + qt16) * 2;
  const float mA = mlP[(base + 0) * 128 + row], lA = mlP[(base + 0) * 128 + 64 + row];
  const float mB = mlP[(base + 1) * 128 + row], lB = mlP[(base + 1) * 128 + 64 + row];
  const float m = fmaxf(mA, mB);
  const float wA = exp2f(mA - m), wB = exp2f(mB - m);
  const float inv = 1.0f / (lA * wA + lB * wB);
  const bf16* pA = oP + (base + 0) * 64 * 128 + row * 128 + qq * 32;
  const bf16* pB = oP + (base + 1) * 64 * 128 + row * 128 + qq * 32;
  const int b = bh >> 4, h = bh & 15;
  const int srow = (16 + qt16) * 64 + row;
  bf16* po = ctx + (size_t)(b * 2048 + srow) * 2048 + h * 128 + qq * 32;
#pragma unroll
  for (int i = 0; i < 4; ++i) {
    bf16x8 a = *(const bf16x8*)(pA + i * 8);
    bf16x8 bb = *(const bf16x8*)(pB + i * 8);
    bf16x8 r;
#pragma unroll
    for (int j = 0; j < 8; ++j)
      r[j] = (bf16)(((float)a[j] * wA + (float)bb[j] * wB) * inv);
    *(bf16x8*)(po + i * 8) = r;
  }
}

extern "C" void kernel_launch(void* const* d_in, const int* in_sizes, int n_in,
                              void* d_out, int out_size, void* d_ws,
                              size_t ws_size, hipStream_t stream) {
  const float* x = (const float*)d_in[0];       // [2,2048,2048]
  const float* qkvw = (const float*)d_in[1];    // [2048,6144]
  const float* qkvb = (const float*)d_in[2];    // [6144]
  const float* ow = (const float*)d_in[3];      // [2048,2048]
  const float* ob = (const float*)d_in[4];      // [2048]
  float* out = (float*)d_out;                   // [2,2048,2048] fp32

  char* ws = (char*)d_ws;
  bf16* xb = (bf16*)(ws);                  // 16.78 MB
  bf16* wqT = (bf16*)(ws + 16777216);      // 25.17 MB (dead after GEMM1)
  bf16* owT = (bf16*)(ws + 41943040);      // 8.39 MB
  bf16* Qbuf = (bf16*)(ws + 50331648);     // 16.78 MB  [B*H][2048][128]
  bf16* Kbuf = (bf16*)(ws + 67108864);     // 16.78 MB  [B*H][2048][128]
  bf16* VTbuf = (bf16*)(ws + 83886080);    // 16.78 MB  [B*H][128][2048]
  bf16* ctxb = xb;                          // reuse: xb dead after GEMM1
  bf16* oP = wqT;                           // reuse: 16.78 MB partials
  float* mlP = (float*)(ws + 16777216 + 16777216);  // 1.05 MB (within wqT)

  // 1) x -> bf16
  k_cvt_f32_bf16<<<8192, 256, 0, stream>>>(x, xb, 2097152);
  // 2) weight transposes (B^T layout for GEMM)
  k_transpose_cvt<<<dim3(96, 32), 256, 0, stream>>>(qkvw, wqT, 2048, 6144);
  k_transpose_cvt<<<dim3(32, 32), 256, 0, stream>>>(ow, owT, 2048, 2048);
  // 3) QKV projection with split head-major epilogue (V transposed)
  k_gemm_bt<6144, 2048, 2><<<dim3(48, 32), 256, 0, stream>>>(
      xb, wqT, qkvb, (void*)Qbuf, (void*)Kbuf, (void*)VTbuf);
  // 4) causal flash attention, 2-way kv-split, barrier-free
  k_attn<<<1024, 256, 0, stream>>>(Qbuf, Kbuf, VTbuf, ctxb, oP, mlP);
  // 4b) merge partials for long q-tiles
  k_merge<<<dim3(16, 32), 256, 0, stream>>>(oP, mlP, ctxb);
  // 5) output projection: out fp32 = ctxb @ owT^T + ob
  k_gemm_bt<2048, 2048, 1><<<dim3(16, 32), 256, 0, stream>>>(
      ctxb, owT, ob, (void*)out, nullptr, nullptr);
}

// Round 10
// 424.368 us; speedup vs baseline: 1.3605x; 1.3605x over previous
//
#include <hip/hip_runtime.h>

typedef __bf16 bf16;
typedef __attribute__((ext_vector_type(8))) __bf16 bf16x8;
typedef __attribute__((ext_vector_type(4))) __bf16 bf16x4;
typedef __attribute__((ext_vector_type(4))) float f32x4;

#define GLL16(gptr, lptr)                                                      \
  __builtin_amdgcn_global_load_lds(                                            \
      (const __attribute__((address_space(1))) void*)(gptr),                   \
      (__attribute__((address_space(3))) void*)(lptr), 16, 0, 0)

__device__ __forceinline__ f32x4 mfma_bf16(bf16x8 a, bf16x8 b, f32x4 c) {
  return __builtin_amdgcn_mfma_f32_16x16x32_bf16(a, b, c, 0, 0, 0);
}

// ---------------- fp32 -> bf16 convert (vectorized) ----------------
__global__ __launch_bounds__(256) void k_cvt_f32_bf16(
    const float* __restrict__ in, bf16* __restrict__ out, int n4) {
  int i = blockIdx.x * blockDim.x + threadIdx.x;
  if (i < n4) {
    f32x4 v = ((const f32x4*)in)[i];
    bf16x4 o;
    o[0] = (bf16)v[0]; o[1] = (bf16)v[1]; o[2] = (bf16)v[2]; o[3] = (bf16)v[3];
    ((bf16x4*)out)[i] = o;
  }
}

// ------------- transpose + convert: out[n][k] = (bf16)in[k][n] -------------
__global__ __launch_bounds__(256) void k_transpose_cvt(
    const float* __restrict__ in, bf16* __restrict__ out, int R, int C) {
  __shared__ float tile[64][65];
  const int t = threadIdx.x;
  const int r0 = blockIdx.y * 64, c0 = blockIdx.x * 64;
  const int tc = t & 63, tr = t >> 6;
#pragma unroll
  for (int i = 0; i < 16; ++i) {
    int r = tr + i * 4;
    tile[r][tc] = in[(size_t)(r0 + r) * C + c0 + tc];
  }
  __syncthreads();
#pragma unroll
  for (int i = 0; i < 16; ++i) {
    int r = tr + i * 4;
    out[(size_t)(c0 + r) * R + r0 + tc] = (bf16)tile[tc][r];
  }
}

// ---------------- bf16 GEMM, B pre-transposed (Bt[N][K]) ----------------
// MODE 0: bf16 flat [M][N]; MODE 1: f32 flat [M][N];
// MODE 2: split head-major QKV — Q,K:[B*H][2048][128]; V TRANSPOSED:
//         VT[B*H][128][2048] so attention staging reads are contiguous.
template <int N, int K, int MODE>
__global__ __launch_bounds__(256) void k_gemm_bt(
    const bf16* __restrict__ A, const bf16* __restrict__ Bt,
    const float* __restrict__ bias, void* __restrict__ C0,
    void* __restrict__ C1, void* __restrict__ C2) {
  __shared__ __align__(16) unsigned char lds[16384];
  unsigned char* ldsA = lds;
  unsigned char* ldsB = lds + 8192;
  const int t = threadIdx.x, w = t >> 6, lane = t & 63;
  const int g = lane >> 4, c15 = lane & 15;
  const int wr = w >> 1, wc = w & 1;
  const int m0 = blockIdx.y * 128, n0 = blockIdx.x * 128;

  const int ch = w * 64 + lane;
  const bf16* gA0 = A + (size_t)(m0 + (ch >> 2)) * K + (ch & 3) * 8;
  const bf16* gA1 = A + (size_t)(m0 + ((ch + 256) >> 2)) * K + (ch & 3) * 8;
  const bf16* gB0 = Bt + (size_t)(n0 + (ch >> 2)) * K + (ch & 3) * 8;
  const bf16* gB1 = Bt + (size_t)(n0 + ((ch + 256) >> 2)) * K + (ch & 3) * 8;
  const unsigned l0 = (unsigned)(w * 64) * 16;

  f32x4 acc[4][4];
#pragma unroll
  for (int m = 0; m < 4; ++m)
#pragma unroll
    for (int n = 0; n < 4; ++n) acc[m][n] = (f32x4){0.f, 0.f, 0.f, 0.f};

  for (int kt = 0; kt < K / 32; ++kt) {
    GLL16(gA0, ldsA + l0);
    GLL16(gA1, ldsA + l0 + 4096);
    GLL16(gB0, ldsB + l0);
    GLL16(gB1, ldsB + l0 + 4096);
    gA0 += 32; gA1 += 32; gB0 += 32; gB1 += 32;
    __syncthreads();

    bf16x8 af[4], bfr[4];
#pragma unroll
    for (int m = 0; m < 4; ++m)
      af[m] = *(const bf16x8*)(ldsA + (wr * 64 + m * 16 + c15) * 64 + g * 16);
#pragma unroll
    for (int n = 0; n < 4; ++n)
      bfr[n] = *(const bf16x8*)(ldsB + (wc * 64 + n * 16 + c15) * 64 + g * 16);
#pragma unroll
    for (int m = 0; m < 4; ++m)
#pragma unroll
      for (int n = 0; n < 4; ++n)
        acc[m][n] = mfma_bf16(af[m], bfr[n], acc[m][n]);
    __syncthreads();
  }

  bf16* sbase = nullptr;
  int sec = 0;
  if constexpr (MODE == 2) {
    sec = n0 >> 11;
    const int hh = (n0 >> 7) & 15;
    sbase = (bf16*)(sec == 0 ? C0 : sec == 1 ? C1 : C2) +
            (size_t)hh * 2048 * 128;
  }

#pragma unroll
  for (int n = 0; n < 4; ++n) {
    const int col = n0 + wc * 64 + n * 16 + c15;
    const float bs = bias[col];
#pragma unroll
    for (int m = 0; m < 4; ++m) {
      if (MODE == 2 && sec == 2) {
        // V: transposed [bh][128][2048]; 4 consecutive srow -> bf16x4 store
        const int row = m0 + wr * 64 + m * 16 + g * 4;
        const int bb = row >> 11, srow = row & 2047;
        const int d = wc * 64 + n * 16 + c15;
        bf16x4 pk;
#pragma unroll
        for (int r = 0; r < 4; ++r) pk[r] = (bf16)(acc[m][n][r] + bs);
        *(bf16x4*)(sbase + (size_t)bb * 16 * 2048 * 128 + (size_t)d * 2048 +
                   srow) = pk;
      } else {
#pragma unroll
        for (int r = 0; r < 4; ++r) {
          const int row = m0 + wr * 64 + m * 16 + g * 4 + r;
          const float v = acc[m][n][r] + bs;
          if constexpr (MODE == 0) {
            ((bf16*)C0)[(size_t)row * N + col] = (bf16)v;
          } else if constexpr (MODE == 1) {
            ((float*)C0)[(size_t)row * N + col] = v;
          } else {
            const int bb = row >> 11, srow = row & 2047;
            const int d = wc * 64 + n * 16 + c15;
            sbase[((size_t)bb * 16 * 2048 + srow) * 128 + d] = (bf16)v;
          }
        }
      }
    }
  }
}

// ---------- causal flash attention, 2-way kv-split, LDS double-buffered ----
// Qb/Kb: [B*H][2048][128] bf16 ; VT: [B*H][128][2048] bf16 (transposed)
// ctx: [B*S][2048] bf16
// oP: [bh][qt16][slot][64][128] bf16 ; mlP: [bh][qt16][slot][2][64] f32
// K tile [64][256B] and V^T tile [128][128B] staged via global_load_lds with
// pre-swizzled global source (rule 21); ds_read_b128 applies the same XOR.
__global__ __launch_bounds__(256) void k_attn(
    const bf16* __restrict__ Qb, const bf16* __restrict__ Kb,
    const bf16* __restrict__ VT, bf16* __restrict__ ctx,
    bf16* __restrict__ oP, float* __restrict__ mlP) {
  __shared__ __align__(16) unsigned char SK[2][16384];  // K[64][128] swz
  __shared__ __align__(16) unsigned char SV[2][16384];  // VT[128][64] swz
  __shared__ __align__(16) unsigned char P[4][2048];    // per-wave P tile
  const int t = threadIdx.x, w = t >> 6, lane = t & 63;
  const int g = lane >> 4, c = lane & 15;
  const int cswz = (c & 7) << 4;
  const int L = (int)blockIdx.x;            // 0..1023
  const int bh = (L & 7) + 8 * (L >> 8);    // same bh -> same XCD (L%8 const)
  const int role = (L >> 3) & 31;
  const int b = bh >> 4, h = bh & 15;
  const size_t hb = (size_t)bh * 2048 * 128;
  const bf16* Qh = Qb + hb;
  const char* Khb = (const char*)(Kb + hb);
  const char* Vhb = (const char*)(VT + hb);
  const float sc = 0.08838834764831845f * 1.4426950408889634f;  // scale*log2e

  // per-lane staging offsets (bytes), tile-invariant
  int kOff[4], vOff[4];
#pragma unroll
  for (int i = 0; i < 4; ++i) {
    const int kr = i * 4 + (lane >> 4);   // row within wave's 16-row K slab
    kOff[i] = kr * 256 + (((lane & 15) * 16) ^ ((kr & 7) << 4));
    const int vr = lane >> 3;             // sub-row within 8-row V slab
    vOff[i] = (w * 32 + i * 8 + vr) * 4096 + (((lane & 7) * 16) ^ (vr << 4));
  }

#define STAGE_TILE(sel, kv0)                                                   \
  {                                                                            \
    const char* kb_ = Khb + (size_t)(kv0) * 256 + w * 4096;                    \
    const char* vb_ = Vhb + (size_t)(kv0) * 2;                                 \
    GLL16(kb_ + kOff[0], &SK[sel][(w * 16 + 0) * 256]);                        \
    GLL16(kb_ + kOff[1], &SK[sel][(w * 16 + 4) * 256]);                        \
    GLL16(kb_ + kOff[2], &SK[sel][(w * 16 + 8) * 256]);                        \
    GLL16(kb_ + kOff[3], &SK[sel][(w * 16 + 12) * 256]);                       \
    GLL16(vb_ + vOff[0], &SV[sel][(w * 32 + 0) * 128]);                        \
    GLL16(vb_ + vOff[1], &SV[sel][(w * 32 + 8) * 128]);                        \
    GLL16(vb_ + vOff[2], &SV[sel][(w * 32 + 16) * 128]);                       \
    GLL16(vb_ + vOff[3], &SV[sel][(w * 32 + 24) * 128]);                       \
  }

  const int nph = (role < 16) ? 1 : 2;
  for (int ph = 0; ph < nph; ++ph) {
    int qt, kv_begin, kv_end, mode;  // mode: 0=ctx, 1=slot0, 2=slot1
    if (role < 16) {
      qt = 31 - role; kv_begin = 0; kv_end = 16; mode = 1;
    } else if (ph == 0) {
      qt = 31 - (role - 16); kv_begin = 16; kv_end = qt + 1; mode = 2;
    } else {
      qt = role - 16; kv_begin = 0; kv_end = qt + 1; mode = 0;
    }
    const int q0 = qt * 64;
    const int qb = q0 + w * 16;

    bf16x8 qf[4];
    {
      const bf16* qp = Qh + (size_t)(qb + c) * 128;
#pragma unroll
      for (int s = 0; s < 4; ++s) qf[s] = *(const bf16x8*)(qp + s * 32 + g * 8);
    }

    f32x4 o[8];
#pragma unroll
    for (int n = 0; n < 8; ++n) o[n] = (f32x4){0.f, 0.f, 0.f, 0.f};
    float mrun[4] = {-3e38f, -3e38f, -3e38f, -3e38f};
    float lrun[4] = {0.f, 0.f, 0.f, 0.f};

    __syncthreads();  // prev phase fully done with LDS before restaging
    STAGE_TILE(0, kv_begin * 64);
    int cur = 0;

    for (int kt = kv_begin; kt < kv_end; ++kt) {
      const int kv0 = kt * 64;
      __syncthreads();  // buf[cur] staged (drains own gll); prev compute done
      if (kt + 1 < kv_end) STAGE_TILE(cur ^ 1, (kt + 1) * 64);  // async

      // S = Q K^T from LDS (swizzled reads, ~2-way max)
      float p[4][4];
      float mt[4] = {-3e38f, -3e38f, -3e38f, -3e38f};
      const bool diag = (kv0 == q0);
#pragma unroll
      for (int tt = 0; tt < 4; ++tt) {
        f32x4 s4 = (f32x4){0.f, 0.f, 0.f, 0.f};
        const unsigned char* kl = &SK[cur][(tt * 16 + c) * 256];
        __builtin_amdgcn_s_setprio(1);
#pragma unroll
        for (int s = 0; s < 4; ++s) {
          bf16x8 kf = *(const bf16x8*)(kl + ((s * 64 + g * 16) ^ cswz));
          s4 = mfma_bf16(qf[s], kf, s4);
        }
        __builtin_amdgcn_s_setprio(0);
        const int kvi = kv0 + tt * 16 + c;
#pragma unroll
        for (int r = 0; r < 4; ++r) {
          float v = s4[r] * sc;
          if (diag) {
            const int qr = qb + g * 4 + r;
            v = (kvi <= qr) ? v : -1e30f;
          }
          p[tt][r] = v;
          mt[r] = fmaxf(mt[r], v);
        }
      }
#pragma unroll
      for (int r = 0; r < 4; ++r) {
        float m = mt[r];
        m = fmaxf(m, __shfl_xor(m, 1));
        m = fmaxf(m, __shfl_xor(m, 2));
        m = fmaxf(m, __shfl_xor(m, 4));
        m = fmaxf(m, __shfl_xor(m, 8));
        mt[r] = m;
      }
      float corr[4];
#pragma unroll
      for (int r = 0; r < 4; ++r) {
        const float mn = fmaxf(mrun[r], mt[r]);
        corr[r] = exp2f(mrun[r] - mn);
        mrun[r] = mn;
      }
#pragma unroll
      for (int r = 0; r < 4; ++r) {
        float s = 0.f;
#pragma unroll
        for (int tt = 0; tt < 4; ++tt) {
          const float e = exp2f(p[tt][r] - mrun[r]);
          p[tt][r] = e;
          s += e;
        }
        s += __shfl_xor(s, 1);
        s += __shfl_xor(s, 2);
        s += __shfl_xor(s, 4);
        s += __shfl_xor(s, 8);
        lrun[r] = lrun[r] * corr[r] + s;
      }
#pragma unroll
      for (int n = 0; n < 8; ++n)
#pragma unroll
        for (int r = 0; r < 4; ++r) o[n][r] *= corr[r];

      // store P (bf16) to per-wave LDS tile (wave-private, no barrier)
#pragma unroll
      for (int tt = 0; tt < 4; ++tt)
#pragma unroll
        for (int r = 0; r < 4; ++r) {
          const int row = g * 4 + r;
          const int colb = (tt * 16 + c) * 2;
          *(bf16*)(&P[w][row * 128 + (colb ^ ((row & 7) << 4))]) =
              (bf16)p[tt][r];
        }

      // PV: o += P(16x64) * V(64x128); V^T fragments from LDS
#pragma unroll
      for (int ks = 0; ks < 2; ++ks) {
        bf16x8 pa = *(const bf16x8*)(&P[w][c * 128 + ((ks * 64 + g * 16) ^ cswz)]);
        __builtin_amdgcn_s_setprio(1);
#pragma unroll
        for (int n = 0; n < 8; ++n) {
          bf16x8 vb = *(const bf16x8*)(&SV[cur][(n * 16 + c) * 128 +
                                                ((ks * 64 + g * 16) ^ cswz)]);
          o[n] = mfma_bf16(pa, vb, o[n]);
        }
        __builtin_amdgcn_s_setprio(0);
      }
      cur ^= 1;
    }

    if (mode == 0) {
      float inv[4];
#pragma unroll
      for (int r = 0; r < 4; ++r) inv[r] = 1.0f / lrun[r];
#pragma unroll
      for (int n = 0; n < 8; ++n)
#pragma unroll
        for (int r = 0; r < 4; ++r) {
          const int row = qb + g * 4 + r;
          ctx[(size_t)(b * 2048 + row) * 2048 + h * 128 + n * 16 + c] =
              (bf16)(o[n][r] * inv[r]);
        }
    } else {
      const int slot = mode - 1;
      const size_t pb = ((size_t)(bh * 16 + (qt - 16)) * 2 + slot);
      bf16* op = oP + pb * 64 * 128;
#pragma unroll
      for (int n = 0; n < 8; ++n)
#pragma unroll
        for (int r = 0; r < 4; ++r) {
          const int row = w * 16 + g * 4 + r;
          op[(size_t)row * 128 + n * 16 + c] = (bf16)o[n][r];  // unnormalized
        }
      if (c == 0) {
        float* mp = mlP + pb * 2 * 64;
#pragma unroll
        for (int r = 0; r < 4; ++r) {
          const int row = w * 16 + g * 4 + r;
          mp[row] = mrun[r];
          mp[64 + row] = lrun[r];
        }
      }
    }
  }
#undef STAGE_TILE
}

// ---------------- merge two kv-split partials -> ctx ----------------
__global__ __launch_bounds__(256) void k_merge(const bf16* __restrict__ oP,
                                               const float* __restrict__ mlP,
                                               bf16* __restrict__ ctx) {
  const int bh = blockIdx.y, qt16 = blockIdx.x;
  const int t = threadIdx.x;
  const int row = t >> 2, qq = t & 3;  // 64 rows x 4 col-quarters
  const size_t base = (size_t)(bh * 16 + qt16) * 2;
  const float mA = mlP[(base + 0) * 128 + row], lA = mlP[(base + 0) * 128 + 64 + row];
  const float mB = mlP[(base + 1) * 128 + row], lB = mlP[(base + 1) * 128 + 64 + row];
  const float m = fmaxf(mA, mB);
  const float wA = exp2f(mA - m), wB = exp2f(mB - m);
  const float inv = 1.0f / (lA * wA + lB * wB);
  const bf16* pA = oP + (base + 0) * 64 * 128 + row * 128 + qq * 32;
  const bf16* pB = oP + (base + 1) * 64 * 128 + row * 128 + qq * 32;
  const int b = bh >> 4, h = bh & 15;
  const int srow = (16 + qt16) * 64 + row;
  bf16* po = ctx + (size_t)(b * 2048 + srow) * 2048 + h * 128 + qq * 32;
#pragma unroll
  for (int i = 0; i < 4; ++i) {
    bf16x8 a = *(const bf16x8*)(pA + i * 8);
    bf16x8 bb = *(const bf16x8*)(pB + i * 8);
    bf16x8 r;
#pragma unroll
    for (int j = 0; j < 8; ++j)
      r[j] = (bf16)(((float)a[j] * wA + (float)bb[j] * wB) * inv);
    *(bf16x8*)(po + i * 8) = r;
  }
}

extern "C" void kernel_launch(void* const* d_in, const int* in_sizes, int n_in,
                              void* d_out, int out_size, void* d_ws,
                              size_t ws_size, hipStream_t stream) {
  const float* x = (const float*)d_in[0];       // [2,2048,2048]
  const float* qkvw = (const float*)d_in[1];    // [2048,6144]
  const float* qkvb = (const float*)d_in[2];    // [6144]
  const float* ow = (const float*)d_in[3];      // [2048,2048]
  const float* ob = (const float*)d_in[4];      // [2048]
  float* out = (float*)d_out;                   // [2,2048,2048] fp32

  char* ws = (char*)d_ws;
  bf16* xb = (bf16*)(ws);                  // 16.78 MB
  bf16* wqT = (bf16*)(ws + 16777216);      // 25.17 MB (dead after GEMM1)
  bf16* owT = (bf16*)(ws + 41943040);      // 8.39 MB
  bf16* Qbuf = (bf16*)(ws + 50331648);     // 16.78 MB  [B*H][2048][128]
  bf16* Kbuf = (bf16*)(ws + 67108864);     // 16.78 MB  [B*H][2048][128]
  bf16* VTbuf = (bf16*)(ws + 83886080);    // 16.78 MB  [B*H][128][2048]
  bf16* ctxb = xb;                          // reuse: xb dead after GEMM1
  bf16* oP = wqT;                           // reuse: 16.78 MB partials
  float* mlP = (float*)(ws + 16777216 + 16777216);  // 1.05 MB (within wqT)

  // 1) x -> bf16
  k_cvt_f32_bf16<<<8192, 256, 0, stream>>>(x, xb, 2097152);
  // 2) weight transposes (B^T layout for GEMM)
  k_transpose_cvt<<<dim3(96, 32), 256, 0, stream>>>(qkvw, wqT, 2048, 6144);
  k_transpose_cvt<<<dim3(32, 32), 256, 0, stream>>>(ow, owT, 2048, 2048);
  // 3) QKV projection with split head-major epilogue (V transposed)
  k_gemm_bt<6144, 2048, 2><<<dim3(48, 32), 256, 0, stream>>>(
      xb, wqT, qkvb, (void*)Qbuf, (void*)Kbuf, (void*)VTbuf);
  // 4) causal flash attention, 2-way kv-split, LDS dbuf pipeline
  k_attn<<<1024, 256, 0, stream>>>(Qbuf, Kbuf, VTbuf, ctxb, oP, mlP);
  // 4b) merge partials for long q-tiles
  k_merge<<<dim3(16, 32), 256, 0, stream>>>(oP, mlP, ctxb);
  // 5) output projection: out fp32 = ctxb @ owT^T + ob
  k_gemm_bt<2048, 2048, 1><<<dim3(16, 32), 256, 0, stream>>>(
      ctxb, owT, ob, (void*)out, nullptr, nullptr);
}